// Round 11
// baseline (54.977 us; speedup 1.0000x reference)
//
#include <hip/hip_runtime.h>
#include <math.h>

#define PX 32            // pixels per block (shared across 3 anchor-waves)
#define NT 192           // 3 waves: wave id == anchor
#define HPX 16           // pixels staged per flush phase
#define LROWS (HPX * 3)  // 48 rows in LDS -> 17280 B -> 9 blocks/CU

// Precise sigmoid: used ONLY for the mask decision sigmoid(p) > thresh.
__device__ __forceinline__ float sigf(float x) { return 1.0f / (1.0f + expf(-x)); }
// Fast value-path math: v_exp_f32 / v_rcp_f32 (rel err ~1e-6, vs 322 absmax budget).
__device__ __forceinline__ float fexp(float x) { return __expf(x); }
__device__ __forceinline__ float fsig(float x) {
    return __builtin_amdgcn_rcpf(1.0f + __expf(-x));
}

template<bool F4>
__device__ __forceinline__ void flushLds(const float* __restrict__ lds,
                                         float* __restrict__ outp, int nfl, int tid)
{
    if (F4) {
        float4* d4 = (float4*)outp;
        const float4* s4 = (const float4*)lds;
        for (int i = tid; i < (nfl >> 2); i += NT) d4[i] = s4[i];
        int rem = nfl & 3, tail = nfl & ~3;
        if (tid < rem) outp[tail + tid] = lds[tail + tid];
    } else {
        float2* d2 = (float2*)outp;
        const float2* s2 = (const float2*)lds;
        for (int i = tid; i < (nfl >> 1); i += NT) d2[i] = s2[i];
    }
}

// Wave a, lane = (h = lane>>5, p = lane&31): row (pixel P0+p, anchor a), entries
// k in [45h, 45h+45). Per j the wave reads two 128B pixel-clusters (full lines).
// Two-phase LDS staging: pixels [0,16) then [16,32) through a [48][90] buffer.
template<int H, int W, int T, bool F4>
__device__ __forceinline__ void decode_level(
    const float* __restrict__ in, const float* __restrict__ anchors,
    float th, float invCase, float* __restrict__ out, long gRowBase,
    int blkL, float* __restrict__ lds)
{
    constexpr int HW = H * W;
    constexpr int SPANS = (HW + PX - 1) / PX;
    const int b    = blkL / SPANS;
    const int P0   = (blkL % SPANS) * PX;
    const int npix = (HW - P0 < PX) ? (HW - P0) : PX;

    const int tid  = threadIdx.x;
    const int a    = tid >> 6;
    const int lane = tid & 63;
    const int h    = lane >> 5;
    const int p    = lane & 31;
    const bool act = (p < npix);

    float v[45];
    if (act) {
        const int pix = P0 + p;
        const int x   = pix % W;
        const int y   = pix / W;
        const float* src = in + ((long)b * 270 + a * 90 + 45 * h) * HW + pix;

        #pragma unroll
        for (int j = 0; j < 45; ++j) v[j] = src[(long)j * HW];
        // MLP fences: force the strided loads to issue in deep batches instead of
        // the compiler's load-few/wait/use sinking (VGPR=36 proved shallow MLP).
        asm volatile("" : "+v"(v[0]), "+v"(v[1]), "+v"(v[2]), "+v"(v[3]), "+v"(v[4]),
                          "+v"(v[5]), "+v"(v[6]), "+v"(v[7]), "+v"(v[8]), "+v"(v[9]),
                          "+v"(v[10]), "+v"(v[11]), "+v"(v[12]), "+v"(v[13]), "+v"(v[14]));
        asm volatile("" : "+v"(v[15]), "+v"(v[16]), "+v"(v[17]), "+v"(v[18]), "+v"(v[19]),
                          "+v"(v[20]), "+v"(v[21]), "+v"(v[22]), "+v"(v[23]), "+v"(v[24]),
                          "+v"(v[25]), "+v"(v[26]), "+v"(v[27]), "+v"(v[28]), "+v"(v[29]));
        asm volatile("" : "+v"(v[30]), "+v"(v[31]), "+v"(v[32]), "+v"(v[33]), "+v"(v[34]),
                          "+v"(v[35]), "+v"(v[36]), "+v"(v[37]), "+v"(v[38]), "+v"(v[39]),
                          "+v"(v[40]), "+v"(v[41]), "+v"(v[42]), "+v"(v[43]), "+v"(v[44]));

        // Per-row scalars: valid on h==0 lanes (their v[0..4] are channels 0..4).
        float sp = sigf(v[0]);              // PRECISE: decides the mask
        bool  m  = sp > th;
        float A0 = anchors[a * 2 + 0], A1 = anchors[a * 2 + 1];
        float w  = A0 * fexp(v[3]);
        float hb = A1 * fexp(v[4]);
        float s  = sqrtf(w * w + hb * hb) * invCase;
        float cx = ((float)x + v[1]) * (float)T;
        float cy = ((float)y + v[2]) * (float)T;

        float ms = __shfl(m ? s : 0.0f, p, 64);       // broadcast h0 -> h1 partner
        float mf = __shfl(m ? 1.0f : 0.0f, p, 64);
        const bool mB = mf > 0.5f;

        #pragma unroll
        for (int j = 0; j < 45; ++j) {
            float val = v[j];
            // k = 45h+j; coord iff k%3==0 (== j%3==0); point region k in [6,18)
            // exists only on h==0 and is all coords scaled by s.
            bool coordAlways = (j % 3 == 0);
            bool pointRegion = (j >= 6 && j < 18);
            if (coordAlways)      v[j] = val * ms;
            else if (pointRegion) v[j] = (h == 0) ? val * ms : (mB ? fsig(val) : 0.0f);
            else                  v[j] = mB ? fsig(val) : 0.0f;
        }
        if (h == 0) {   // obj entries 0..5 override (local m/s valid on h==0)
            v[0] = m ? (float)b : 0.0f;
            v[1] = m ? sp       : 0.0f;
            v[2] = m ? cx       : 0.0f;
            v[3] = m ? cy       : 0.0f;
            v[4] = m ? w        : 0.0f;
            v[5] = m ? hb       : 0.0f;
        }
    }

    const size_t gbase = (size_t)(gRowBase + ((long)b * HW + P0) * 3) * 90;

    // ---- phase A: pixels [0, HPX) ----
    if (act && p < HPX) {
        float* dst = lds + (p * 3 + a) * 90 + 45 * h;
        #pragma unroll
        for (int j = 0; j < 45; ++j) dst[j] = v[j];
    }
    __syncthreads();
    int npixA = npix < HPX ? npix : HPX;
    flushLds<F4>(lds, out + gbase, npixA * 3 * 90, tid);

    // ---- phase B: pixels [HPX, PX) ----
    int npixB = npix - HPX;
    if (npixB > 0) {
        __syncthreads();
        if (act && p >= HPX) {
            float* dst = lds + ((p - HPX) * 3 + a) * 90 + 45 * h;
            #pragma unroll
            for (int j = 0; j < 45; ++j) dst[j] = v[j];
        }
        __syncthreads();
        flushLds<F4>(lds, out + gbase + (size_t)LROWS * 90, npixB * 3 * 90, tid);
    }
}

__global__ __launch_bounds__(NT, 6) void decode_all(
    const float* __restrict__ in13, const float* __restrict__ in26,
    const float* __restrict__ in52,
    const float* __restrict__ anc13, const float* __restrict__ anc26,
    const float* __restrict__ anc52,
    const float* __restrict__ thresh, const int* __restrict__ casep,
    float* __restrict__ out, int nblk52, int nblk26, long rows13, long rows26)
{
    __shared__ float lds[LROWS * 90];
    const float th = thresh[0];
    const float invCase = 1.0f / (float)(*casep);
    const int blk = blockIdx.x;

    if (blk < nblk52)
        decode_level<52, 52, 8, true>(in52, anc52, th, invCase, out,
                                      rows13 + rows26, blk, lds);
    else if (blk < nblk52 + nblk26)
        decode_level<26, 26, 16, true>(in26, anc26, th, invCase, out,
                                       rows13, blk - nblk52, lds);
    else
        decode_level<13, 13, 32, false>(in13, anc13, th, invCase, out,
                                        0, blk - nblk52 - nblk26, lds);
}

extern "C" void kernel_launch(void* const* d_in, const int* in_sizes, int n_in,
                              void* d_out, int out_size, void* d_ws, size_t ws_size,
                              hipStream_t stream) {
    const float* in13  = (const float*)d_in[0];
    const float* in26  = (const float*)d_in[1];
    const float* in52  = (const float*)d_in[2];
    const float* anc13 = (const float*)d_in[3];
    const float* anc26 = (const float*)d_in[4];
    const float* anc52 = (const float*)d_in[5];
    const float* th    = (const float*)d_in[6];
    const int*   casep = (const int*)d_in[7];
    float* out = (float*)d_out;

    int B = in_sizes[0] / (270 * 13 * 13);   // 32

    long rows13 = (long)B * 13 * 13 * 3;
    long rows26 = (long)B * 26 * 26 * 3;

    int nblk13 = B * ((13 * 13 + PX - 1) / PX);    // 32*6   = 192
    int nblk26 = B * ((26 * 26 + PX - 1) / PX);    // 32*22  = 704
    int nblk52 = B * ((52 * 52 + PX - 1) / PX);    // 32*85  = 2720

    decode_all<<<dim3(nblk52 + nblk26 + nblk13), dim3(NT), 0, stream>>>(
        in13, in26, in52, anc13, anc26, anc52, th, casep, out,
        nblk52, nblk26, rows13, rows26);
}

// Round 12
// 54.181 us; speedup vs baseline: 1.0147x; 1.0147x over previous
//
#include <hip/hip_runtime.h>
#include <math.h>

#define PX 32            // pixels per block (shared across 3 anchor-waves)
#define NT 192           // 3 waves: wave id == anchor
#define HPX 16           // pixels staged per flush phase
#define LROWS (HPX * 3)  // 48 rows in LDS -> 17280 B -> 9 blocks/CU

// Precise sigmoid: used ONLY for the mask decision sigmoid(p) > thresh.
__device__ __forceinline__ float sigf(float x) { return 1.0f / (1.0f + expf(-x)); }
// Fast value-path math: v_exp_f32 / v_rcp_f32 (rel err ~1e-6, vs 322 absmax budget).
__device__ __forceinline__ float fexp(float x) { return __expf(x); }
__device__ __forceinline__ float fsig(float x) {
    return __builtin_amdgcn_rcpf(1.0f + __expf(-x));
}

template<bool F4>
__device__ __forceinline__ void flushLds(const float* __restrict__ lds,
                                         float* __restrict__ outp, int nfl, int tid)
{
    if (F4) {
        float4* d4 = (float4*)outp;
        const float4* s4 = (const float4*)lds;
        for (int i = tid; i < (nfl >> 2); i += NT) d4[i] = s4[i];
        int rem = nfl & 3, tail = nfl & ~3;
        if (tid < rem) outp[tail + tid] = lds[tail + tid];
    } else {
        float2* d2 = (float2*)outp;
        const float2* s2 = (const float2*)lds;
        for (int i = tid; i < (nfl >> 1); i += NT) d2[i] = s2[i];
    }
}

// Wave a, lane = (h = lane>>5, p = lane&31): row (pixel P0+p, anchor a), entries
// k in [45h, 45h+45). Per j the wave reads two 128B pixel-clusters (full lines).
// Two-phase LDS staging: pixels [0,16) then [16,32) through a [48][90] buffer.
template<int H, int W, int T, bool F4>
__device__ __forceinline__ void decode_level(
    const float* __restrict__ in, const float* __restrict__ anchors,
    float th, float invCase, float* __restrict__ out, long gRowBase,
    int blkL, float* __restrict__ lds)
{
    constexpr int HW = H * W;
    constexpr int SPANS = (HW + PX - 1) / PX;
    const int b    = blkL / SPANS;
    const int P0   = (blkL % SPANS) * PX;
    const int npix = (HW - P0 < PX) ? (HW - P0) : PX;

    const int tid  = threadIdx.x;
    const int a    = tid >> 6;
    const int lane = tid & 63;
    const int h    = lane >> 5;
    const int p    = lane & 31;
    const bool act = (p < npix);

    float v[45];
    if (act) {
        const int pix = P0 + p;
        const int x   = pix % W;
        const int y   = pix / W;
        const float* src = in + ((long)b * 270 + a * 90 + 45 * h) * HW + pix;

        #pragma unroll
        for (int j = 0; j < 45; ++j) v[j] = src[(long)j * HW];

        // Per-row scalars: valid on h==0 lanes (their v[0..4] are channels 0..4).
        float sp = sigf(v[0]);              // PRECISE: decides the mask
        bool  m  = sp > th;
        float A0 = anchors[a * 2 + 0], A1 = anchors[a * 2 + 1];
        float w  = A0 * fexp(v[3]);
        float hb = A1 * fexp(v[4]);
        float s  = sqrtf(w * w + hb * hb) * invCase;
        float cx = ((float)x + v[1]) * (float)T;
        float cy = ((float)y + v[2]) * (float)T;

        float ms = __shfl(m ? s : 0.0f, p, 64);       // broadcast h0 -> h1 partner
        float mf = __shfl(m ? 1.0f : 0.0f, p, 64);
        const bool mB = mf > 0.5f;

        #pragma unroll
        for (int j = 0; j < 45; ++j) {
            float val = v[j];
            // k = 45h+j; coord iff k%3==0 (== j%3==0); point region k in [6,18)
            // exists only on h==0 and is all coords scaled by s.
            bool coordAlways = (j % 3 == 0);
            bool pointRegion = (j >= 6 && j < 18);
            if (coordAlways)      v[j] = val * ms;
            else if (pointRegion) v[j] = (h == 0) ? val * ms : (mB ? fsig(val) : 0.0f);
            else                  v[j] = mB ? fsig(val) : 0.0f;
        }
        if (h == 0) {   // obj entries 0..5 override (local m/s valid on h==0)
            v[0] = m ? (float)b : 0.0f;
            v[1] = m ? sp       : 0.0f;
            v[2] = m ? cx       : 0.0f;
            v[3] = m ? cy       : 0.0f;
            v[4] = m ? w        : 0.0f;
            v[5] = m ? hb       : 0.0f;
        }
    }

    const size_t gbase = (size_t)(gRowBase + ((long)b * HW + P0) * 3) * 90;

    // ---- phase A: pixels [0, HPX) ----
    if (act && p < HPX) {
        float* dst = lds + (p * 3 + a) * 90 + 45 * h;
        #pragma unroll
        for (int j = 0; j < 45; ++j) dst[j] = v[j];
    }
    __syncthreads();
    int npixA = npix < HPX ? npix : HPX;
    flushLds<F4>(lds, out + gbase, npixA * 3 * 90, tid);

    // ---- phase B: pixels [HPX, PX) ----
    int npixB = npix - HPX;
    if (npixB > 0) {
        __syncthreads();
        if (act && p >= HPX) {
            float* dst = lds + ((p - HPX) * 3 + a) * 90 + 45 * h;
            #pragma unroll
            for (int j = 0; j < 45; ++j) dst[j] = v[j];
        }
        __syncthreads();
        flushLds<F4>(lds, out + gbase + (size_t)LROWS * 90, npixB * 3 * 90, tid);
    }
}

__global__ __launch_bounds__(NT, 6) void decode_all(
    const float* __restrict__ in13, const float* __restrict__ in26,
    const float* __restrict__ in52,
    const float* __restrict__ anc13, const float* __restrict__ anc26,
    const float* __restrict__ anc52,
    const float* __restrict__ thresh, const int* __restrict__ casep,
    float* __restrict__ out, int nblk52, int nblk26, long rows13, long rows26)
{
    __shared__ float lds[LROWS * 90];
    const float th = thresh[0];
    const float invCase = 1.0f / (float)(*casep);
    const int blk = blockIdx.x;

    if (blk < nblk52)
        decode_level<52, 52, 8, true>(in52, anc52, th, invCase, out,
                                      rows13 + rows26, blk, lds);
    else if (blk < nblk52 + nblk26)
        decode_level<26, 26, 16, true>(in26, anc26, th, invCase, out,
                                       rows13, blk - nblk52, lds);
    else
        decode_level<13, 13, 32, false>(in13, anc13, th, invCase, out,
                                        0, blk - nblk52 - nblk26, lds);
}

extern "C" void kernel_launch(void* const* d_in, const int* in_sizes, int n_in,
                              void* d_out, int out_size, void* d_ws, size_t ws_size,
                              hipStream_t stream) {
    const float* in13  = (const float*)d_in[0];
    const float* in26  = (const float*)d_in[1];
    const float* in52  = (const float*)d_in[2];
    const float* anc13 = (const float*)d_in[3];
    const float* anc26 = (const float*)d_in[4];
    const float* anc52 = (const float*)d_in[5];
    const float* th    = (const float*)d_in[6];
    const int*   casep = (const int*)d_in[7];
    float* out = (float*)d_out;

    int B = in_sizes[0] / (270 * 13 * 13);   // 32

    long rows13 = (long)B * 13 * 13 * 3;
    long rows26 = (long)B * 26 * 26 * 3;

    int nblk13 = B * ((13 * 13 + PX - 1) / PX);    // 32*6   = 192
    int nblk26 = B * ((26 * 26 + PX - 1) / PX);    // 32*22  = 704
    int nblk52 = B * ((52 * 52 + PX - 1) / PX);    // 32*85  = 2720

    decode_all<<<dim3(nblk52 + nblk26 + nblk13), dim3(NT), 0, stream>>>(
        in13, in26, in52, anc13, anc26, anc52, th, casep, out,
        nblk52, nblk26, rows13, rows26);
}